// Round 6
// baseline (132.964 us; speedup 1.0000x reference)
//
#include <hip/hip_runtime.h>
#include <math.h>
#include <stdint.h>

#define B_SZ 2048
#define N_SZ 16384
#define D_SZ 64
#define P_SZ 5

#define BM 128
#define BN 128
#define NCB (N_SZ / BN)
#define NT  4                 // item tiles per block
#define INVLN2 1.44269504088896340736f
#define LN2    0.69314718055994530942f

typedef __bf16 bf16x8 __attribute__((ext_vector_type(8)));
typedef __bf16 bf16x4 __attribute__((ext_vector_type(4)));
typedef float f32x4 __attribute__((ext_vector_type(4)));

// ws layout (float units)
#define WS_S    0
#define WS_POS  (WS_S + B_SZ)
#define WS_U2   (WS_POS + B_SZ)
#define WS_V2   (WS_U2 + B_SZ)
#define WS_UBF  (WS_V2 + N_SZ)
#define WS_VBF  (WS_UBF + B_SZ * D_SZ / 2)

#define GLD_LDS(g, s) __builtin_amdgcn_global_load_lds( \
    (const __attribute__((address_space(1))) void*)(g), \
    (__attribute__((address_space(3))) void*)(s), 16, 0, 0)

// swizzled byte offset of 16B-group g16 in row `row` of a [128][64]bf16 tile
#define SWZ(row, g16) (((row) << 7) + ((((g16) ^ ((row) & 7))) << 4))

// ---- prep: fp32 -> swizzled bf16 rows + norms. 16 lanes per row. ----
__global__ __launch_bounds__(256) void prep_k(const float* __restrict__ uem,
                                              const float* __restrict__ vem,
                                              float* __restrict__ ws) {
    const int rid = blockIdx.x * 16 + (threadIdx.x >> 4);
    const int seg = threadIdx.x & 15;
    const bool isU = rid < B_SZ;
    const int r = isU ? rid : rid - B_SZ;
    const float* src = (isU ? uem : vem) + (size_t)r * D_SZ;
    float4 x = ((const float4*)src)[seg];
    float nrm = x.x * x.x + x.y * x.y + x.z * x.z + x.w * x.w;
#pragma unroll
    for (int o = 1; o < 16; o <<= 1) nrm += __shfl_xor(nrm, o);
    uint16_t* dst = (uint16_t*)(ws + (isU ? WS_UBF : WS_VBF)) + (size_t)r * D_SZ;
    int g = seg >> 1, p = seg & 1, r7 = r & 7;
    int off = (((g ^ r7) << 3) + (p << 2));
    bf16x4 h = {(__bf16)x.x, (__bf16)x.y, (__bf16)x.z, (__bf16)x.w};
    *(bf16x4*)(dst + off) = h;
    if (seg == 0) {
        if (isU) ws[WS_U2 + r] = nrm;
        else     ws[WS_V2 + r] = nrm;
    }
}

__global__ __launch_bounds__(256, 3) void dist2_k(const float* __restrict__ target,
                                                  const int* __restrict__ iidx,
                                                  const int* __restrict__ pidx,
                                                  float* __restrict__ ws) {
    __shared__ __bf16 bufs[2][BM * D_SZ];      // 32 KB, double-buffered V (buf0 = U at start)
    __shared__ int ids[BM * 6];                // 3 KB: p0..p4, own id per user
    __shared__ float u2s[BM];
    __shared__ float msgs[BM];
    __shared__ int colids[2][BN];
    __shared__ float colv2s[2][BN];
    __shared__ unsigned long long flagw[2][2]; // per-tile column flag bits (64 cols/word)
    __shared__ unsigned int bloom[512];        // 16384-bit filter over user-side ids

    const int t = threadIdx.x;
    const int orig = blockIdx.x;               // 512 blocks
    const int xcd = orig & 7, i2 = orig >> 3;
    const int bxg = xcd * 4 + (i2 & 3);        // item-tile group 0..31 (XCD slab)
    const int by = i2 >> 2;                    // user block 0..15
    const int brow = by * BM;
    const int bx0 = bxg * NT;

    float* wsS = ws + WS_S;
    float* pos = ws + WS_POS;
    const float* u2 = ws + WS_U2;
    const float* v2 = ws + WS_V2;
    const uint16_t* ubf = (const uint16_t*)(ws + WS_UBF);
    const uint16_t* vbf = (const uint16_t*)(ws + WS_VBF);

    const int w = t >> 6, l = t & 63;

    bloom[t] = 0u;
    bloom[256 + t] = 0u;

    // stage U -> bufs[0], V tile0 -> bufs[1]
    {
        const char* gu = (const char*)(ubf + (size_t)brow * D_SZ) + w * 4096 + l * 16;
        const char* gv = (const char*)(vbf + (size_t)bx0 * BN * D_SZ) + w * 4096 + l * 16;
        char* lu = (char*)&bufs[0][0] + w * 4096;
        char* lv = (char*)&bufs[1][0] + w * 4096;
#pragma unroll
        for (int i = 0; i < 4; ++i) {
            GLD_LDS(gu + i * 1024, lu + i * 1024);
            GLD_LDS(gv + i * 1024, lv + i * 1024);
        }
    }
    int uid0 = 0, uid1 = 0, uid2 = 0, uid3 = 0, uid4 = 0, uid5 = 0;
    if (t < BM) {
        int U = brow + t;
        float tg = target[U];
        float sg = (tg > 0.f) ? 1.f : ((tg < 0.f) ? -1.f : 0.f);
        u2s[t] = u2[U];
        msgs[t] = -0.5f * INVLN2 * sg;
        const int* pp = pidx + (size_t)U * P_SZ;
        uid0 = pp[0]; uid1 = pp[1]; uid2 = pp[2]; uid3 = pp[3]; uid4 = pp[4];
        uid5 = iidx[U];
        int* d = &ids[t * 6];
        d[0] = uid0; d[1] = uid1; d[2] = uid2; d[3] = uid3; d[4] = uid4; d[5] = uid5;
        colids[1][t] = iidx[bx0 * BN + t];
        colv2s[1][t] = v2[bx0 * BN + t];
    }
    __syncthreads();                           // bar1: tiles + scalars in LDS, bloom zeroed
    if (t < BM) {
#define BOR(id) atomicOr(&bloom[((unsigned)(id) & 16383u) >> 5], 1u << ((unsigned)(id) & 31))
        BOR(uid0); BOR(uid1); BOR(uid2); BOR(uid3); BOR(uid4); BOR(uid5);
#undef BOR
    }
    __syncthreads();                           // bar2: bloom ready
    // tile0 column flags (waves 0,1 cover the 128 columns)
    if (w < 2) {
        unsigned int h = (unsigned)colids[1][t] & 16383u;
        bool fl = (bloom[h >> 5] >> (h & 31)) & 1u;
        unsigned long long bal = __ballot(fl);
        if (l == 0) flagw[1][w] = bal;
    }
    const int wi = w >> 1, wu = w & 1, lr = l & 15, kg = l >> 4;
    // U fragments -> registers (held for all tiles); frees bufs[0]
    bf16x8 bu[2][4];
#pragma unroll
    for (int kk = 0; kk < 2; ++kk)
#pragma unroll
        for (int ut = 0; ut < 4; ++ut)
            bu[kk][ut] = *(const bf16x8*)((const char*)&bufs[0][0] +
                                          SWZ(wu * 64 + ut * 16 + lr, kk * 4 + kg));
    __syncthreads();                           // bar3: flags visible, bufs[0] free

    float Ssum[4] = {0.f, 0.f, 0.f, 0.f};

#pragma unroll
    for (int j = 0; j < NT; ++j) {
        const int cur = (j + 1) & 1, nxt = j & 1;
        const int bx = bx0 + j, bcol = bx * BN;
        const bool pf = (j + 1 < NT);
        int nid = 0; float nv2 = 0.f;
        if (pf) {                              // issue next-tile stage + scalar prefetch
            const char* gv = (const char*)(vbf + (size_t)(bcol + BN) * D_SZ) + w * 4096 + l * 16;
            char* lv = (char*)&bufs[nxt][0] + w * 4096;
#pragma unroll
            for (int i = 0; i < 4; ++i) GLD_LDS(gv + i * 1024, lv + i * 1024);
            if (w < 2) { nid = iidx[bcol + BN + t]; nv2 = v2[bcol + BN + t]; }
        }
        // ---- MFMA tile j ----
        f32x4 acc[4][4];
#pragma unroll
        for (int it = 0; it < 4; ++it)
#pragma unroll
            for (int ut = 0; ut < 4; ++ut)
                acc[it][ut] = (f32x4){0.f, 0.f, 0.f, 0.f};
        const char* Vb = (const char*)&bufs[cur][0];
#pragma unroll
        for (int kk = 0; kk < 2; ++kk) {
            bf16x8 afk[4];
#pragma unroll
            for (int it = 0; it < 4; ++it)
                afk[it] = *(const bf16x8*)(Vb + SWZ(wi * 64 + it * 16 + lr, kk * 4 + kg));
#pragma unroll
            for (int ut = 0; ut < 4; ++ut)
#pragma unroll
                for (int it = 0; it < 4; ++it)
                    acc[it][ut] = __builtin_amdgcn_mfma_f32_16x16x32_bf16(afk[it], bu[kk][ut],
                                                                          acc[it][ut], 0, 0, 0);
        }
        // next-tile column metadata (latency of nid/nv2 hidden under MFMA)
        if (pf && w < 2) {
            unsigned int h = (unsigned)nid & 16383u;
            bool fl = (bloom[h >> 5] >> (h & 31)) & 1u;
            unsigned long long bal = __ballot(fl);
            colids[nxt][t] = nid;
            colv2s[nxt][t] = nv2;
            if (l == 0) flagw[nxt][w] = bal;
        }
        // ---- epilogue tile j: logits<=0 -> plain exp2 sum, flags gate rare masking ----
        const unsigned long long fmask = flagw[cur][wi];
        const bool diag = (bx == by);
        f32x4 v2q[4];
#pragma unroll
        for (int it = 0; it < 4; ++it)
            v2q[it] = *(const f32x4*)&colv2s[cur][wi * 64 + it * 16 + kg * 4];
#pragma unroll
        for (int ut = 0; ut < 4; ++ut) {
            const int ur = wu * 64 + ut * 16 + lr;
            const float u2r = u2s[ur];
            const float msg2 = msgs[ur];
            float Sl = 0.f;
#pragma unroll
            for (int it = 0; it < 4; ++it) {
#pragma unroll
                for (int r = 0; r < 4; ++r) {
                    float d2 = fmaf(-2.f, acc[it][ut][r], u2r + v2q[it][r]);
                    float v = fmaxf(d2, 0.f) * msg2;
                    float e = exp2f(v);
                    const int bit = it * 16 + kg * 4 + r;
                    if ((fmask >> bit) & 1ull) {       // rare: column maybe-masked
                        int c = colids[cur][wi * 64 + bit];
                        const int* uid = &ids[ur * 6];
                        if ((c == uid[0]) | (c == uid[1]) | (c == uid[2]) |
                            (c == uid[3]) | (c == uid[4]) | (c == uid[5])) e = 0.f;
                    }
                    if (diag && (bcol + wi * 64 + bit == brow + ur))
                        pos[brow + ur] = v;            // pre-mask diagonal (log2 domain)
                    Sl += e;
                }
            }
            Ssum[ut] += Sl;
        }
        __syncthreads();                       // drains stage j+1; protects buffer swap
    }

    // ---- final reduce + one atomic per (user, wi-half) ----
#pragma unroll
    for (int ut = 0; ut < 4; ++ut) {
        float S = Ssum[ut];
        S += __shfl_xor(S, 16);
        S += __shfl_xor(S, 32);
        if (kg == 0) atomicAdd(&wsS[brow + wu * 64 + ut * 16 + lr], S);
    }
}

__global__ __launch_bounds__(256) void finish_k(const float* __restrict__ target,
                                                const float* __restrict__ ws,
                                                float* __restrict__ out) {
    const int r = blockIdx.x * 256 + threadIdx.x;
    float p2 = ws[WS_POS + r];
    float S = ws[WS_S + r];
    float ce = LN2 * (__log2f(exp2f(p2) + S) - p2);
    float c = ce * fabsf(target[r]);
#pragma unroll
    for (int o = 32; o > 0; o >>= 1) c += __shfl_down(c, o);
    __shared__ float sred[4];
    if ((threadIdx.x & 63) == 0) sred[threadIdx.x >> 6] = c;
    __syncthreads();
    if (threadIdx.x == 0)
        atomicAdd(out, sred[0] + sred[1] + sred[2] + sred[3]);
}

extern "C" void kernel_launch(void* const* d_in, const int* in_sizes, int n_in,
                              void* d_out, int out_size, void* d_ws, size_t ws_size,
                              hipStream_t stream) {
    const float* uem = (const float*)d_in[0];
    const float* vem = (const float*)d_in[1];
    const float* target = (const float*)d_in[2];
    const int* iidx = (const int*)d_in[3];
    const int* pidx = (const int*)d_in[4];
    float* ws = (float*)d_ws;
    float* out = (float*)d_out;

    hipMemsetAsync(out, 0, sizeof(float), stream);
    hipMemsetAsync(ws + WS_S, 0, B_SZ * sizeof(float), stream);

    prep_k<<<dim3((B_SZ + N_SZ) / 16), dim3(256), 0, stream>>>(uem, vem, ws);

    dist2_k<<<dim3((NCB / NT) * (B_SZ / BM)), dim3(256), 0, stream>>>(target, iidx, pidx, ws);

    finish_k<<<dim3(B_SZ / 256), dim3(256), 0, stream>>>(target, ws, out);
}

// Round 7
// 48.633 us; speedup vs baseline: 2.7340x; 2.7340x over previous
//
#include <hip/hip_runtime.h>
#include <math.h>
#include <stdint.h>

#define B_SZ 2048
#define N_SZ 16384
#define D_SZ 64
#define P_SZ 5

#define BM 128
#define BN 128
#define NCB (N_SZ / BN)
#define INVLN2 1.44269504088896340736f
#define LN2    0.69314718055994530942f

typedef __bf16 bf16x8 __attribute__((ext_vector_type(8)));
typedef float f32x4 __attribute__((ext_vector_type(4)));

// ws layout (float units)
#define WS_S    0                           // [2048] per-row sum of exp2(masked logits)
#define WS_POS  (WS_S + B_SZ)               // [2048] diagonal logit (log2 domain)
#define WS_U2   (WS_POS + B_SZ)             // [2048]
#define WS_V2   (WS_U2 + B_SZ)              // [16384]
#define WS_UF   (WS_V2 + N_SZ)              // bf16 frag-order: [128 g][2 kk][64 lane][8]
#define WS_VF   (WS_UF + B_SZ * D_SZ / 2)   // bf16 frag-order: [1024 g][2 kk][64 lane][8]

// ---- prep: fp32 -> fragment-ordered bf16 + norms. 8 lanes per row. ----
// frag layout: for 16-row group g, K-step kk, lane l=(kg*16+lr):
//   16B at bf16-offset ((g*2+kk)*64 + l)*8  holds row (g*16+lr), k=[kk*32+kg*8, +8)
__global__ __launch_bounds__(256) void prep_k(const float* __restrict__ uem,
                                              const float* __restrict__ vem,
                                              float* __restrict__ ws) {
    const int tid = blockIdx.x * 256 + threadIdx.x;
    const int rid = tid >> 3, grp = tid & 7;
    const bool isU = rid < B_SZ;
    const int r = isU ? rid : rid - B_SZ;
    const float* src = (isU ? uem : vem) + (size_t)r * D_SZ + grp * 8;
    float4 a = ((const float4*)src)[0];
    float4 b = ((const float4*)src)[1];
    float nrm = a.x * a.x + a.y * a.y + a.z * a.z + a.w * a.w +
                b.x * b.x + b.y * b.y + b.z * b.z + b.w * b.w;
#pragma unroll
    for (int o = 1; o < 8; o <<= 1) nrm += __shfl_xor(nrm, o);
    const int g = r >> 4, lr = r & 15, kk = grp >> 2, kg = grp & 3;
    uint16_t* dst = (uint16_t*)(ws + (isU ? WS_UF : WS_VF));
    size_t off8 = ((size_t)(g * 2 + kk) * 64 + kg * 16 + lr) * 8;
    bf16x8 h = {(__bf16)a.x, (__bf16)a.y, (__bf16)a.z, (__bf16)a.w,
                (__bf16)b.x, (__bf16)b.y, (__bf16)b.z, (__bf16)b.w};
    *(bf16x8*)(dst + off8) = h;
    if (grp == 0) {
        if (isU) ws[WS_U2 + r] = nrm;
        else     ws[WS_V2 + r] = nrm;
    }
}

__global__ __launch_bounds__(256, 3) void dist_k(const float* __restrict__ target,
                                                 const int* __restrict__ iidx,
                                                 const int* __restrict__ pidx,
                                                 float* __restrict__ ws) {
    __shared__ float u2s[BM];
    __shared__ float msgs[BM];
    __shared__ int ids[BM * 6];
    __shared__ float colv2[BN];
    __shared__ int colid[BN];
    __shared__ unsigned int bloom[512];      // 16384-bit filter over tile column ids
    __shared__ unsigned int uflag[BM];

    const int t = threadIdx.x;
    const int orig = blockIdx.x;
    const int bx = (orig & 7) * 16 + ((orig >> 3) & 15);   // item block (XCD slab swizzle)
    const int by = orig >> 7;                              // user block
    const int brow = by * BM, bcol = bx * BN;

    float* wsS = ws + WS_S;
    float* pos = ws + WS_POS;
    const float* u2 = ws + WS_U2;
    const float* v2 = ws + WS_V2;
    const uint16_t* uf = (const uint16_t*)(ws + WS_UF);
    const uint16_t* vf = (const uint16_t*)(ws + WS_VF);

    bloom[t] = 0u;
    bloom[256 + t] = 0u;
    if (t < BM) {
        int U = brow + t;
        float tg = target[U];
        float sg = (tg > 0.f) ? 1.f : ((tg < 0.f) ? -1.f : 0.f);
        u2s[t] = u2[U];
        msgs[t] = -0.5f * INVLN2 * sg;
        const int* pp = pidx + (size_t)U * P_SZ;
        int* d = &ids[t * 6];
        d[0] = pp[0]; d[1] = pp[1]; d[2] = pp[2]; d[3] = pp[3]; d[4] = pp[4];
        d[5] = iidx[U];
        colid[t] = iidx[bcol + t];
        colv2[t] = v2[bcol + t];
    }
    __syncthreads();                         // bar1: scalars + bloom-zero
    if (t < BN) {
        unsigned int h = (unsigned)colid[t] & 16383u;
        atomicOr(&bloom[h >> 5], 1u << (h & 31));
    }
    __syncthreads();                         // bar2: bloom built
    if (t < BM) {
        unsigned int fl = 0u;
#pragma unroll
        for (int j = 0; j < 6; ++j) {
            unsigned int h = (unsigned)ids[t * 6 + j] & 16383u;
            fl |= (bloom[h >> 5] >> (h & 31)) & 1u;
        }
        uflag[t] = fl;
    }

    // ---- MFMA: fragments straight from global (L2-hot), no LDS, no barriers ----
    const int w = t >> 6, l = t & 63;
    const int wi = w >> 1, wu = w & 1, lr = l & 15, kg = l >> 4;

    f32x4 acc[4][4];                         // [it][ut]
#pragma unroll
    for (int it = 0; it < 4; ++it)
#pragma unroll
        for (int ut = 0; ut < 4; ++ut)
            acc[it][ut] = (f32x4){0.f, 0.f, 0.f, 0.f};

    const int gv0 = (bcol >> 4) + wi * 4;    // item 16-groups
    const int gu0 = (brow >> 4) + wu * 4;    // user 16-groups
#pragma unroll
    for (int kk = 0; kk < 2; ++kk) {
        bf16x8 av[4];
#pragma unroll
        for (int it = 0; it < 4; ++it)
            av[it] = *(const bf16x8*)(vf + ((size_t)((gv0 + it) * 2 + kk) * 64 + l) * 8);
#pragma unroll
        for (int ut = 0; ut < 4; ++ut) {
            bf16x8 bu = *(const bf16x8*)(uf + ((size_t)((gu0 + ut) * 2 + kk) * 64 + l) * 8);
#pragma unroll
            for (int it = 0; it < 4; ++it)
                acc[it][ut] = __builtin_amdgcn_mfma_f32_16x16x32_bf16(av[it], bu, acc[it][ut], 0, 0, 0);
        }
    }
    __syncthreads();                         // bar3: uflag visible

    // ---- epilogue: logits<=0 (sign in {0,1}) -> plain exp2 sum; bloom gates masking ----
    f32x4 v2q[4];
#pragma unroll
    for (int it = 0; it < 4; ++it)
        v2q[it] = *(const f32x4*)&colv2[wi * 64 + it * 16 + kg * 4];
    const bool diag = (bx == by);

#pragma unroll
    for (int ut = 0; ut < 4; ++ut) {
        const int ur = wu * 64 + ut * 16 + lr;   // user = C col (lane&15)
        const float u2r = u2s[ur];
        const float msg2 = msgs[ur];
        const unsigned int fl = uflag[ur];
        int q0, q1, q2, q3, q4, q5;
        if (fl) {
            const int* d = &ids[ur * 6];
            q0 = d[0]; q1 = d[1]; q2 = d[2]; q3 = d[3]; q4 = d[4]; q5 = d[5];
        }
        float Sl = 0.f;
#pragma unroll
        for (int it = 0; it < 4; ++it) {
#pragma unroll
            for (int r = 0; r < 4; ++r) {
                float d2 = fmaf(-2.f, acc[it][ut][r], u2r + v2q[it][r]);
                float v = fmaxf(d2, 0.f) * msg2;     // log2-domain logit, <= 0
                float e = exp2f(v);
                if (fl) {
                    int c = colid[wi * 64 + it * 16 + kg * 4 + r];
                    if ((c == q0) | (c == q1) | (c == q2) |
                        (c == q3) | (c == q4) | (c == q5)) e = 0.f;
                }
                if (diag && (bcol + wi * 64 + it * 16 + kg * 4 + r == brow + ur))
                    pos[brow + ur] = v;              // pre-mask diagonal
                Sl += e;
            }
        }
        Sl += __shfl_xor(Sl, 16);
        Sl += __shfl_xor(Sl, 32);
        if (kg == 0) atomicAdd(&wsS[brow + ur], Sl);
    }
}

__global__ __launch_bounds__(256) void finish_k(const float* __restrict__ target,
                                                const float* __restrict__ ws,
                                                float* __restrict__ out) {
    const int r = blockIdx.x * 256 + threadIdx.x;
    float p2 = ws[WS_POS + r];
    float S = ws[WS_S + r];
    float ce = LN2 * (__log2f(exp2f(p2) + S) - p2);
    float c = ce * fabsf(target[r]);
#pragma unroll
    for (int o = 32; o > 0; o >>= 1) c += __shfl_down(c, o);
    __shared__ float sred[4];
    if ((threadIdx.x & 63) == 0) sred[threadIdx.x >> 6] = c;
    __syncthreads();
    if (threadIdx.x == 0)
        atomicAdd(out, sred[0] + sred[1] + sred[2] + sred[3]);
}

extern "C" void kernel_launch(void* const* d_in, const int* in_sizes, int n_in,
                              void* d_out, int out_size, void* d_ws, size_t ws_size,
                              hipStream_t stream) {
    const float* uem = (const float*)d_in[0];
    const float* vem = (const float*)d_in[1];
    const float* target = (const float*)d_in[2];
    const int* iidx = (const int*)d_in[3];
    const int* pidx = (const int*)d_in[4];
    float* ws = (float*)d_ws;
    float* out = (float*)d_out;

    hipMemsetAsync(out, 0, sizeof(float), stream);
    hipMemsetAsync(ws + WS_S, 0, B_SZ * sizeof(float), stream);

    prep_k<<<dim3((B_SZ + N_SZ) * 8 / 256), dim3(256), 0, stream>>>(uem, vem, ws);

    dist_k<<<dim3(NCB * (B_SZ / BM)), dim3(256), 0, stream>>>(target, iidx, pidx, ws);

    finish_k<<<dim3(B_SZ / 256), dim3(256), 0, stream>>>(target, ws, out);
}

// Round 8
// 45.113 us; speedup vs baseline: 2.9473x; 1.0780x over previous
//
#include <hip/hip_runtime.h>
#include <math.h>
#include <stdint.h>

#define B_SZ 2048
#define N_SZ 16384
#define D_SZ 64
#define P_SZ 5

#define BM 128
#define BN 128
#define NCB (N_SZ / BN)
#define INVLN2 1.44269504088896340736f
#define LN2    0.69314718055994530942f

typedef __bf16 bf16x8 __attribute__((ext_vector_type(8)));
typedef __bf16 bf16x4 __attribute__((ext_vector_type(4)));
typedef float f32x4 __attribute__((ext_vector_type(4)));

// ws layout (float units)
#define WS_S    0                           // [2048] per-row sum of exp2(masked logits)
#define WS_POS  (WS_S + B_SZ)               // [2048] diagonal logit (log2 domain)
#define WS_U2   (WS_POS + B_SZ)             // [2048]
#define WS_V2   (WS_U2 + B_SZ)              // [16384]
#define WS_UBF  (WS_V2 + N_SZ)              // bf16[2048*64], swizzled rows
#define WS_VBF  (WS_UBF + B_SZ * D_SZ / 2)  // bf16[16384*64], swizzled rows

__device__ __forceinline__ float fexp2(float x) { return __builtin_amdgcn_exp2f(x); }

#define GLD_LDS(g, s) __builtin_amdgcn_global_load_lds( \
    (const __attribute__((address_space(1))) void*)(g), \
    (__attribute__((address_space(3))) void*)(s), 16, 0, 0)

// swizzled byte offset of 16B-group g16 in row `row` of a [128][64]bf16 tile
#define SWZ(row, g16) (((row) << 7) + ((((g16) ^ ((row) & 7))) << 4))

// ---- prep: fp32 -> swizzled bf16 rows + norms; also zeroes the S accumulators ----
__global__ __launch_bounds__(256) void prep_k(const float* __restrict__ uem,
                                              const float* __restrict__ vem,
                                              float* __restrict__ ws) {
    if (blockIdx.x < B_SZ / 256) ws[WS_S + blockIdx.x * 256 + threadIdx.x] = 0.f;
    const int rid = blockIdx.x * 16 + (threadIdx.x >> 4);
    const int seg = threadIdx.x & 15;
    const bool isU = rid < B_SZ;
    const int r = isU ? rid : rid - B_SZ;
    const float* src = (isU ? uem : vem) + (size_t)r * D_SZ;
    float4 x = ((const float4*)src)[seg];
    float nrm = x.x * x.x + x.y * x.y + x.z * x.z + x.w * x.w;
#pragma unroll
    for (int o = 1; o < 16; o <<= 1) nrm += __shfl_xor(nrm, o);
    uint16_t* dst = (uint16_t*)(ws + (isU ? WS_UBF : WS_VBF)) + (size_t)r * D_SZ;
    int g = seg >> 1, p = seg & 1, r7 = r & 7;
    int off = (((g ^ r7) << 3) + (p << 2));
    bf16x4 h = {(__bf16)x.x, (__bf16)x.y, (__bf16)x.z, (__bf16)x.w};
    *(bf16x4*)(dst + off) = h;
    if (seg == 0) {
        if (isU) ws[WS_U2 + r] = nrm;
        else     ws[WS_V2 + r] = nrm;
    }
}

__global__ __launch_bounds__(256, 4) void dist_k(const float* __restrict__ target,
                                                 const int* __restrict__ iidx,
                                                 const int* __restrict__ pidx,
                                                 float* __restrict__ ws) {
    __shared__ __bf16 Ut[BM * D_SZ];         // 16 KB, swizzled rows
    __shared__ __bf16 Vt[BN * D_SZ];         // 16 KB, swizzled rows
    __shared__ float u2s[BM];
    __shared__ float msgs[BM];
    __shared__ int ids[BM * 6];              // p0..p4 + own id per user
    __shared__ float colv2[BN];
    __shared__ int colid[BN];
    __shared__ unsigned int bloom[512];      // 16384-bit filter over USER-side ids (768)
    __shared__ unsigned long long flagw[2];  // per wi-half: flagged-column bits

    const int t = threadIdx.x;
    const int orig = blockIdx.x;
    const int bx = (orig & 7) * 16 + ((orig >> 3) & 15);   // item block (XCD slab)
    const int by = orig >> 7;                              // user block
    const int brow = by * BM, bcol = bx * BN;

    float* wsS = ws + WS_S;
    float* pos = ws + WS_POS;
    const float* u2 = ws + WS_U2;
    const float* v2 = ws + WS_V2;
    const uint16_t* ubf = (const uint16_t*)(ws + WS_UBF);
    const uint16_t* vbf = (const uint16_t*)(ws + WS_VBF);

    const int w = t >> 6, l = t & 63;

    bloom[t] = 0u;
    bloom[256 + t] = 0u;

    // ---- async stage: linear copy of pre-swizzled bf16 tiles ----
    {
        const char* gu = (const char*)(ubf + (size_t)brow * D_SZ) + w * 4096 + l * 16;
        const char* gv = (const char*)(vbf + (size_t)bcol * D_SZ) + w * 4096 + l * 16;
        char* lu = (char*)Ut + w * 4096;
        char* lv = (char*)Vt + w * 4096;
#pragma unroll
        for (int i = 0; i < 4; ++i) {
            GLD_LDS(gu + i * 1024, lu + i * 1024);
            GLD_LDS(gv + i * 1024, lv + i * 1024);
        }
    }
    if (t < BM) {
        int U = brow + t;
        float tg = target[U];
        float sg = (tg > 0.f) ? 1.f : ((tg < 0.f) ? -1.f : 0.f);
        u2s[t] = u2[U];
        msgs[t] = -0.5f * INVLN2 * sg;       // log2-domain sign factor (<= 0)
        const int* pp = pidx + (size_t)U * P_SZ;
        int* d = &ids[t * 6];
        d[0] = pp[0]; d[1] = pp[1]; d[2] = pp[2]; d[3] = pp[3]; d[4] = pp[4];
        d[5] = iidx[U];
        colid[t] = iidx[bcol + t];
        colv2[t] = v2[bcol + t];
    }
    __syncthreads();                         // bar1: tiles staged (vmcnt drained) + scalars
    if (t < BM) {
        const int* d = &ids[t * 6];
#pragma unroll
        for (int j = 0; j < 6; ++j) {
            unsigned int h = (unsigned)d[j] & 16383u;
            atomicOr(&bloom[h >> 5], 1u << (h & 31));
        }
    }
    __syncthreads();                         // bar2: bloom built
    if (w < 2) {                             // column flag bits for each wi-half
        unsigned int h = (unsigned)colid[w * 64 + l] & 16383u;
        bool f = (bloom[h >> 5] >> (h & 31)) & 1u;
        unsigned long long bal = __ballot(f);
        if (l == 0) flagw[w] = bal;
    }

    // ---- MFMA: A=items, B=users, frags from swizzled LDS ----
    const int wi = w >> 1, wu = w & 1, lr = l & 15, kg = l >> 4;
    const char* UtB = (const char*)Ut;
    const char* VtB = (const char*)Vt;
    f32x4 acc[4][4];                         // [it][ut]
#pragma unroll
    for (int it = 0; it < 4; ++it)
#pragma unroll
        for (int ut = 0; ut < 4; ++ut)
            acc[it][ut] = (f32x4){0.f, 0.f, 0.f, 0.f};
#pragma unroll
    for (int kk = 0; kk < 2; ++kk) {
        bf16x8 afk[4];
#pragma unroll
        for (int it = 0; it < 4; ++it)
            afk[it] = *(const bf16x8*)(VtB + SWZ(wi * 64 + it * 16 + lr, kk * 4 + kg));
#pragma unroll
        for (int ut = 0; ut < 4; ++ut) {
            bf16x8 bu = *(const bf16x8*)(UtB + SWZ(wu * 64 + ut * 16 + lr, kk * 4 + kg));
#pragma unroll
            for (int it = 0; it < 4; ++it)
                acc[it][ut] = __builtin_amdgcn_mfma_f32_16x16x32_bf16(afk[it], bu, acc[it][ut], 0, 0, 0);
        }
    }
    __syncthreads();                         // bar3: flagw visible

    // ---- epilogue: branch-free exp2 sum; rare masked columns subtracted ----
    f32x4 v2q[4];
    unsigned nib[4];
    const unsigned long long fm = flagw[wi];
#pragma unroll
    for (int it = 0; it < 4; ++it) {
        v2q[it] = *(const f32x4*)&colv2[wi * 64 + it * 16 + kg * 4];
        nib[it] = ((unsigned)(fm >> (it * 16 + kg * 4))) & 0xFu;
    }
    const bool diag = (bx == by);

#pragma unroll
    for (int ut = 0; ut < 4; ++ut) {
        const int ur = wu * 64 + ut * 16 + lr;   // user = C col (lane&15)
        const float u2r = u2s[ur];
        const float msg2 = msgs[ur];
        const float c1 = -2.f * msg2;            // >= 0
        float Sl = 0.f;
#pragma unroll
        for (int it = 0; it < 4; ++it) {
            f32x4 bt;
#pragma unroll
            for (int r = 0; r < 4; ++r) bt[r] = (u2r + v2q[it][r]) * msg2;
#pragma unroll
            for (int r = 0; r < 4; ++r) {
                // v = msg2 * max(d2,0) = min(msg2*d2, 0)  (msg2 <= 0)
                float v = fminf(fmaf(c1, acc[it][ut][r], bt[r]), 0.f);
                Sl += fexp2(v);
            }
            if (nib[it]) {                       // rare: some column in this group flagged
                const int* q = &ids[ur * 6];
#pragma unroll
                for (int r = 0; r < 4; ++r) {
                    if ((nib[it] >> r) & 1u) {
                        int c = colid[wi * 64 + it * 16 + kg * 4 + r];
                        if ((c == q[0]) | (c == q[1]) | (c == q[2]) |
                            (c == q[3]) | (c == q[4]) | (c == q[5])) {
                            float v = fminf(fmaf(c1, acc[it][ut][r], bt[r]), 0.f);
                            Sl -= fexp2(v);      // remove masked term (exact same value)
                        }
                    }
                }
            }
            if (diag) {                          // 16/2048 blocks
#pragma unroll
                for (int r = 0; r < 4; ++r) {
                    if (bcol + wi * 64 + it * 16 + kg * 4 + r == brow + ur) {
                        float v = fminf(fmaf(c1, acc[it][ut][r], bt[r]), 0.f);
                        pos[brow + ur] = v;      // pre-mask diagonal (log2 domain)
                    }
                }
            }
        }
        Sl += __shfl_xor(Sl, 16);
        Sl += __shfl_xor(Sl, 32);
        if (kg == 0) atomicAdd(&wsS[brow + ur], Sl);
    }
}

// single block: no out-memset, no atomics
__global__ __launch_bounds__(256) void finish_k(const float* __restrict__ target,
                                                const float* __restrict__ ws,
                                                float* __restrict__ out) {
    float c = 0.f;
    for (int r = threadIdx.x; r < B_SZ; r += 256) {
        float p2 = ws[WS_POS + r];
        float S = ws[WS_S + r];
        float ce = LN2 * (__log2f(fexp2(p2) + S) - p2);
        c += ce * fabsf(target[r]);
    }
#pragma unroll
    for (int o = 32; o > 0; o >>= 1) c += __shfl_down(c, o);
    __shared__ float sred[4];
    if ((threadIdx.x & 63) == 0) sred[threadIdx.x >> 6] = c;
    __syncthreads();
    if (threadIdx.x == 0)
        out[0] = sred[0] + sred[1] + sred[2] + sred[3];
}

extern "C" void kernel_launch(void* const* d_in, const int* in_sizes, int n_in,
                              void* d_out, int out_size, void* d_ws, size_t ws_size,
                              hipStream_t stream) {
    const float* uem = (const float*)d_in[0];
    const float* vem = (const float*)d_in[1];
    const float* target = (const float*)d_in[2];
    const int* iidx = (const int*)d_in[3];
    const int* pidx = (const int*)d_in[4];
    float* ws = (float*)d_ws;
    float* out = (float*)d_out;

    prep_k<<<dim3((B_SZ + N_SZ) / 16), dim3(256), 0, stream>>>(uem, vem, ws);

    dist_k<<<dim3(NCB * (B_SZ / BM)), dim3(256), 0, stream>>>(target, iidx, pidx, ws);

    finish_k<<<dim3(1), dim3(256), 0, stream>>>(target, ws, out);
}